// Round 9
// baseline (17.349 us; speedup 1.0000x reference)
//
#include <hip/hip_runtime.h>

#define HW_BIG   1e10f
#define LOSS_EPS 1e-8f

typedef unsigned long long u64;

// ---------------------------------------------------------------------------
// distance (in pixels) to nearest set bit in a 256-bit row mask rm[4] from
// position y. Returns 32768 if the row is empty. Exact.
// ---------------------------------------------------------------------------
__device__ __forceinline__ int row_nearest(const u64* rm, int y) {
    const int yw = y >> 6, yb = y & 63;
    int dd = 32768;
    u64 w = rm[yw] & (~0ULL >> (63 - yb));
    int j = yw;
    while (w == 0 && j > 0) w = rm[--j];
    if (w) dd = y - (j * 64 + 63 - __builtin_clzll(w));
    u64 w2 = rm[yw] & (~0ULL << yb);
    int j2 = yw;
    while (w2 == 0 && j2 < 3) w2 = rm[++j2];
    if (w2) { int du = (j2 * 64 + __builtin_ctzll(w2)) - y; dd = min(dd, du); }
    return dd;
}

// ---------------------------------------------------------------------------
// Kernel 1: pure streaming mask builder. 256 threads/block, 1 pixel/thread,
// fully coalesced loads, ballot -> one u64 store per wave per array.
//   mv: predicted mask bits (sigmoid(v)>0.5 <=> v>0)
//   ml: label mask bits (t is exactly 0/1)
// Word layout: flat word index = pixel_index >> 6  ==  [img][x][yword].
// ---------------------------------------------------------------------------
__global__ void k_masks(const float* __restrict__ inp,
                        const float* __restrict__ tgt,
                        u64* __restrict__ mv,
                        u64* __restrict__ ml) {
    const size_t gid = (size_t)blockIdx.x * 256 + threadIdx.x;
    const bool vb = inp[gid] > 0.0f;
    const bool tb = tgt[gid] > 0.5f;
    const u64 bv = __ballot(vb);
    const u64 bt = __ballot(tb);
    if ((threadIdx.x & 63) == 0) {
        mv[gid >> 6] = bv;
        ml[gid >> 6] = bt;
    }
}

// ---------------------------------------------------------------------------
// Kernel 2 (boundary + DT + loss, 8 y-rows/block): block = (img, 8 y-rows),
// 1024 threads = (x = tid>>2, yq = tid&3); each thread handles pixels
// (x, y0+yq) and (x, y0+yq+4).
// Stage whole-image mask words (2x8 KB) -> derive both boundary-bit arrays
// word-parallel in LDS (zero-padded 4-neighbor rule, 1 word/thread/mask) ->
// per pixel G[x][yr] = (nearest boundary bit in row x from y)^2 -> exact
// early-exit outward scan over x' -> fused weight + focal BCE (fast
// __expf/__logf) -> deterministic 16-wave block reduction.
// ---------------------------------------------------------------------------
__global__ void k_dt_loss(const float* __restrict__ inp,
                          const u64* __restrict__ mv,
                          const u64* __restrict__ ml,
                          float* __restrict__ partials) {
    __shared__ u64 Mv[1024];       // [row x][yword] predicted-mask bits
    __shared__ u64 Ml[1024];       // label-mask bits
    __shared__ u64 Bib[1024];      // predicted-image boundary bits
    __shared__ u64 Blb[1024];      // label boundary bits
    __shared__ float G1[256][8];   // g indexed [x'][yr]
    __shared__ float G2[256][8];
    __shared__ float wsum[16];
    const int tid = threadIdx.x;
    const int img = blockIdx.x >> 5;
    const int y0  = (blockIdx.x & 31) * 8;
    const int x   = tid >> 2;           // 0..255
    const int yq  = tid & 3;            // 0..3
    const int ya  = y0 + yq;
    const int yb  = ya + 4;

    const size_t mbase = (size_t)img * 1024;
    Mv[tid] = mv[mbase + tid];
    Ml[tid] = ml[mbase + tid];
    // 4 consecutive lanes read 16 contiguous bytes (x uniform per lane quad)
    const float va = inp[((size_t)img * 256 + x) * 256 + ya];
    const float vb = inp[((size_t)img * 256 + x) * 256 + yb];
    __syncthreads();

    // boundary words in LDS: tid = (row x)*4 + word j. Zero padding at image
    // borders; cross-word carries within the row. Identical formula to the
    // previous k_masks (bit-exact).
    {
        const int xr_ = tid >> 2, j = tid & 3;
        u64 own = Mv[tid];
        u64 up  = (xr_ > 0)   ? Mv[tid - 4] : 0ULL;
        u64 dn  = (xr_ < 255) ? Mv[tid + 4] : 0ULL;
        u64 lf  = (own << 1) | ((j > 0) ? (Mv[tid - 1] >> 63) : 0ULL);
        u64 rt  = (own >> 1) | ((j < 3) ? (Mv[tid + 1] << 63) : 0ULL);
        Bib[tid] = own & ~(up & dn & lf & rt);
        own = Ml[tid];
        up  = (xr_ > 0)   ? Ml[tid - 4] : 0ULL;
        dn  = (xr_ < 255) ? Ml[tid + 4] : 0ULL;
        lf  = (own << 1) | ((j > 0) ? (Ml[tid - 1] >> 63) : 0ULL);
        rt  = (own >> 1) | ((j < 3) ? (Ml[tid + 1] << 63) : 0ULL);
        Blb[tid] = own & ~(up & dn & lf & rt);
    }
    __syncthreads();

    const int ywa = ya >> 6, yba = ya & 63;
    const int ywb = yb >> 6, ybb = yb & 63;
    const bool fibA = (Bib[x * 4 + ywa] >> yba) & 1;
    const bool flbA = (Blb[x * 4 + ywa] >> yba) & 1;
    const float tA  = ((Ml[x * 4 + ywa] >> yba) & 1) ? 1.0f : 0.0f;
    const bool fibB = (Bib[x * 4 + ywb] >> ybb) & 1;
    const bool flbB = (Blb[x * 4 + ywb] >> ybb) & 1;
    const float tB  = ((Ml[x * 4 + ywb] >> ybb) & 1) ? 1.0f : 0.0f;

    {
        const int d1a = row_nearest(&Bib[x * 4], ya);
        const int d2a = row_nearest(&Blb[x * 4], ya);
        const int d1b = row_nearest(&Bib[x * 4], yb);
        const int d2b = row_nearest(&Blb[x * 4], yb);
        G1[x][yq]     = (d1a > 255) ? HW_BIG : (float)(d1a * d1a);
        G2[x][yq]     = (d2a > 255) ? HW_BIG : (float)(d2a * d2a);
        G1[x][yq + 4] = (d1b > 255) ? HW_BIG : (float)(d1b * d1b);
        G2[x][yq + 4] = (d2b > 255) ? HW_BIG : (float)(d2b * d2b);
    }
    __syncthreads();

    // exact early-exit outward scans over x' = x -+ d (per pixel). Lanes that
    // don't consume a distance (m1 used only where flb, m2 where fib) init to
    // 0 so they never prolong the scan.
    float m1a = flbA ? G1[x][yq] : 0.0f;
    float m2a = fibA ? G2[x][yq] : 0.0f;
    for (int d = 1; d < 256; ++d) {
        const float fd2 = (float)(d * d);          // exact integer in f32
        if (fd2 >= m1a && fd2 >= m2a) break;
        const int xl = x - d;
        if (xl >= 0)  { m1a = fminf(m1a, G1[xl][yq] + fd2); m2a = fminf(m2a, G2[xl][yq] + fd2); }
        const int xr = x + d;
        if (xr < 256) { m1a = fminf(m1a, G1[xr][yq] + fd2); m2a = fminf(m2a, G2[xr][yq] + fd2); }
    }
    float m1b = flbB ? G1[x][yq + 4] : 0.0f;
    float m2b = fibB ? G2[x][yq + 4] : 0.0f;
    for (int d = 1; d < 256; ++d) {
        const float fd2 = (float)(d * d);
        if (fd2 >= m1b && fd2 >= m2b) break;
        const int xl = x - d;
        if (xl >= 0)  { m1b = fminf(m1b, G1[xl][yq + 4] + fd2); m2b = fminf(m2b, G2[xl][yq + 4] + fd2); }
        const int xr = x + d;
        if (xr < 256) { m1b = fminf(m1b, G1[xr][yq + 4] + fd2); m2b = fminf(m2b, G2[xr][yq + 4] + fd2); }
    }

    // fused weight + focal BCE (GAMMA=1, THETA=1, SIGMA=1), fast intrinsics
    const float pa = 1.0f / (1.0f + __expf(-va));
    float wA = 1.0f;
    if (flbA) wA += __expf(-sqrtf(m1a));
    if (fibA) wA += __expf(-sqrtf(m2a));
    float lossA = wA * (-(1.0f - pa) * tA * __logf(pa + LOSS_EPS)
                        - pa * (1.0f - tA) * __logf(1.0f - pa + LOSS_EPS));

    const float pb = 1.0f / (1.0f + __expf(-vb));
    float wB = 1.0f;
    if (flbB) wB += __expf(-sqrtf(m1b));
    if (fibB) wB += __expf(-sqrtf(m2b));
    float lossB = wB * (-(1.0f - pb) * tB * __logf(pb + LOSS_EPS)
                        - pb * (1.0f - tB) * __logf(1.0f - pb + LOSS_EPS));

    // deterministic block reduction: wave shfl tree + 16 wave partials
    float s = lossA + lossB;
#pragma unroll
    for (int off = 32; off > 0; off >>= 1) s += __shfl_down(s, off, 64);
    if ((tid & 63) == 0) wsum[tid >> 6] = s;
    __syncthreads();
    if (tid == 0) {
        float bs = 0.0f;
#pragma unroll
        for (int i = 0; i < 16; ++i) bs += wsum[i];
        partials[blockIdx.x] = bs;
    }
}

// ---------------------------------------------------------------------------
// Kernel 3: reduce partials -> mean (single block, fixed order, double accum)
// ---------------------------------------------------------------------------
__global__ void k_reduce(const float* __restrict__ partials, int n,
                         float* __restrict__ out, double inv_count) {
    __shared__ double sw[4];
    const int tid = threadIdx.x;
    double s = 0.0;
    for (int i = tid; i < n; i += 256) s += (double)partials[i];
#pragma unroll
    for (int off = 32; off > 0; off >>= 1) s += __shfl_down(s, off, 64);
    const int lane = tid & 63, wv = tid >> 6;
    if (lane == 0) sw[wv] = s;
    __syncthreads();
    if (tid == 0) out[0] = (float)(((sw[0] + sw[1]) + (sw[2] + sw[3])) * inv_count);
}

// ---------------------------------------------------------------------------
extern "C" void kernel_launch(void* const* d_in, const int* in_sizes, int n_in,
                              void* d_out, int out_size, void* d_ws, size_t ws_size,
                              hipStream_t stream) {
    const float* inp = (const float*)d_in[0];
    const float* tgt = (const float*)d_in[1];
    float* out = (float*)d_out;

    const int total = in_sizes[0];          // B*256*256
    const int nimg  = total / 65536;        // B = 8
    const int nblk1 = total / 256;          // 2048 blocks (masks, 256 thr)
    const int nblk2 = nimg * 32;            // 256 blocks (DT+loss, 8 rows each)

    char* ws = (char*)d_ws;
    u64*   mv    = (u64*)ws;                          // nimg*1024 u64 each
    u64*   ml    = mv + (size_t)nimg * 1024;
    float* parts = (float*)(ml + (size_t)nimg * 1024);

    k_masks  <<<nblk1, 256,  0, stream>>>(inp, tgt, mv, ml);
    k_dt_loss<<<nblk2, 1024, 0, stream>>>(inp, mv, ml, parts);
    k_reduce <<<1,     256,  0, stream>>>(parts, nblk2, out, 1.0 / (double)total);
}